// Round 17
// baseline (77.380 us; speedup 1.0000x reference)
//
#include <hip/hip_runtime.h>
#include <stdint.h>

typedef short short8 __attribute__((ext_vector_type(8)));
typedef short short4v __attribute__((ext_vector_type(4)));
typedef float f32x4 __attribute__((ext_vector_type(4)));
typedef unsigned int u32x2 __attribute__((ext_vector_type(2)));
typedef unsigned int u32x4 __attribute__((ext_vector_type(4)));
typedef unsigned short u16;
typedef unsigned int u32;

#define T_ 2048
#define QK_SCALE 0.180336878f   // 0.125 * log2(e): softmax in log2 domain

__device__ inline u16 f2bf(float f) {
  unsigned u = __builtin_bit_cast(unsigned, f);
  u += 0x7fffu + ((u >> 16) & 1u);   // RNE; inputs finite
  return (u16)(u >> 16);
}

__device__ inline u32 cvt_pk_bf16(float lo, float hi) {
  u32 r;
  asm("v_cvt_pk_bf16_f32 %0, %1, %2" : "=v"(r) : "v"(lo), "v"(hi));
  return r;
}

__device__ inline f32x4 mfma_bf16(short8 a, short8 b, f32x4 c) {
  return __builtin_amdgcn_mfma_f32_16x16x32_bf16(a, b, c, 0, 0, 0);
}

// async global->LDS, 16B per lane; lds base must be wave-uniform
__device__ inline void gload16(const u16* g, u16* l) {
  __builtin_amdgcn_global_load_lds(
      (const __attribute__((address_space(1))) void*)g,
      (__attribute__((address_space(3))) void*)l, 16, 0, 0);
}

// ---------------- prep: transpose-convert both weights (x handled in-GEMM) ----------------

__device__ inline void tile_transpose(const float* __restrict__ W, u16* __restrict__ Wt,
                                      int R, int Ccols, int c0, int r0, int t,
                                      float (*tile)[33]) {
  int tr = t >> 3, tc = (t & 7) * 4;
  float4 v = *(const float4*)&W[(size_t)(r0 + tr) * Ccols + c0 + tc];
  tile[tr][tc + 0] = v.x; tile[tr][tc + 1] = v.y;
  tile[tr][tc + 2] = v.z; tile[tr][tc + 3] = v.w;
  __syncthreads();
  short4v o;
#pragma unroll
  for (int i = 0; i < 4; ++i) o[i] = (short)f2bf(tile[tc + i][tr]);
  *(short4v*)&Wt[(size_t)(c0 + tr) * R + r0 + tc] = o;
}

__global__ __launch_bounds__(256) void prep_kernel(const float* __restrict__ Wqkv,
                                                   const float* __restrict__ Wproj,
                                                   u16* __restrict__ wqkvT,
                                                   u16* __restrict__ wprojT) {
  __shared__ float tile[32][33];
  int bid = blockIdx.x, t = threadIdx.x;
  if (bid < 1728) {
    tile_transpose(Wqkv, wqkvT, 768, 2304, (bid % 72) * 32, (bid / 72) * 32, t, tile);
  } else {
    int t3 = bid - 1728;
    tile_transpose(Wproj, wprojT, 768, 768, (t3 % 24) * 32, (t3 / 24) * 32, t, tile);
  }
}

// ---------------- MTILE x 128 GEMM, LDS dbuf, 1 barrier/iter ----------------
// MODE 0 (MTILE=64): A = x fp32, converted in-staging (issue loads early,
// convert+ds_write after MFMA phase — latency hidden); qkv epilogue.
// MODE 1 (MTILE=32): A bf16 via gload16; proj epilogue.

template <int MODE, int MTILE>
__global__ __launch_bounds__(256) void gemm_kernel(const float* __restrict__ X,
                                                   const u16* __restrict__ A,
                                                   const u16* __restrict__ Bt,
                                                   const float* __restrict__ bias,
                                                   u16* __restrict__ qb,
                                                   u16* __restrict__ kb,
                                                   u16* __restrict__ vpb,
                                                   float* __restrict__ out) {
  constexpr int MF = MTILE / 32;            // m-fragments per wave
  constexpr int ABUF = MTILE * 64;          // per-buffer A size (u16)
  __shared__ u16 S[2 * ABUF + 2 * 8192];    // As dbuf | Bs dbuf
  u16* As = S;
  u16* Bs = S + 2 * ABUF;
  int tid = threadIdx.x, w = tid >> 6, l = tid & 63, lg = l >> 4, lr = l & 15;
  int nwg = gridDim.x * gridDim.y;
  int hw = blockIdx.y * gridDim.x + blockIdx.x;
  int logical = (hw & 7) * (nwg >> 3) + (hw >> 3);
  int n0 = (logical % gridDim.x) * 128, m0 = (logical / gridDim.x) * MTILE;
  int wm = (w >> 1) * (MTILE / 2), wn = (w & 1) * 64;
  f32x4 acc[MF][4] = {};
  int rsub = l >> 3;
  int sc = ((l & 7) ^ rsub) * 8;

  // prologue: stage tile 0 into buf 0
#pragma unroll
  for (int j = 0; j < MF; ++j) {
    int row = w * (MTILE / 4) + j * 8 + rsub;
    if constexpr (MODE == 0) {
      const float* src = &X[(size_t)(m0 + row) * 768 + sc];
      float4 a0 = *(const float4*)src;
      float4 a1 = *(const float4*)(src + 4);
      u32x4 cv;
      cv[0] = cvt_pk_bf16(a0.x, a0.y);
      cv[1] = cvt_pk_bf16(a0.z, a0.w);
      cv[2] = cvt_pk_bf16(a1.x, a1.y);
      cv[3] = cvt_pk_bf16(a1.z, a1.w);
      *(u32x4*)&As[(w * MF + j) * 512 + l * 8] = cv;
    } else {
      gload16(&A[(size_t)(m0 + row) * 768 + sc], &As[(w * MF + j) * 512]);
    }
  }
#pragma unroll
  for (int j = 0; j < 4; ++j) {
    int row = w * 32 + j * 8 + rsub;
    gload16(&Bt[(size_t)(n0 + row) * 768 + sc], &Bs[(w * 4 + j) * 512]);
  }
  __syncthreads();

  for (int kt = 0; kt < 12; ++kt) {
    int p = kt & 1;
    float4 af[MF][2];
    if (kt + 1 < 12) {
      int k1 = (kt + 1) * 64;
#pragma unroll
      for (int j = 0; j < MF; ++j) {
        int row = w * (MTILE / 4) + j * 8 + rsub;
        if constexpr (MODE == 0) {
          const float* src = &X[(size_t)(m0 + row) * 768 + k1 + sc];
          af[j][0] = *(const float4*)src;          // issued before MFMA phase
          af[j][1] = *(const float4*)(src + 4);
        } else {
          gload16(&A[(size_t)(m0 + row) * 768 + k1 + sc], &As[(p ^ 1) * ABUF + (w * MF + j) * 512]);
        }
      }
#pragma unroll
      for (int j = 0; j < 4; ++j) {
        int row = w * 32 + j * 8 + rsub;
        gload16(&Bt[(size_t)(n0 + row) * 768 + k1 + sc], &Bs[(p ^ 1) * 8192 + (w * 4 + j) * 512]);
      }
    }
    const u16* Ap = As + p * ABUF;
    const u16* Bp = Bs + p * 8192;
    short8 a[MF][2], b[4][2];
#pragma unroll
    for (int h = 0; h < 2; ++h) {
#pragma unroll
      for (int mf = 0; mf < MF; ++mf) {
        int cw = ((h * 4 + lg) ^ (lr & 7)) * 8;
        a[mf][h] = *(const short8*)&Ap[(wm + mf * 16 + lr) * 64 + cw];
      }
#pragma unroll
      for (int nf = 0; nf < 4; ++nf) {
        int cw = ((h * 4 + lg) ^ (lr & 7)) * 8;
        b[nf][h] = *(const short8*)&Bp[(wn + nf * 16 + lr) * 64 + cw];
      }
    }
#pragma unroll
    for (int h = 0; h < 2; ++h)
#pragma unroll
      for (int mf = 0; mf < MF; ++mf)
#pragma unroll
        for (int nf = 0; nf < 4; ++nf)
          acc[mf][nf] = mfma_bf16(a[mf][h], b[nf][h], acc[mf][nf]);
    if constexpr (MODE == 0) {
      if (kt + 1 < 12) {   // convert + write AFTER compute (loads have landed)
#pragma unroll
        for (int j = 0; j < MF; ++j) {
          u32x4 cv;
          cv[0] = cvt_pk_bf16(af[j][0].x, af[j][0].y);
          cv[1] = cvt_pk_bf16(af[j][0].z, af[j][0].w);
          cv[2] = cvt_pk_bf16(af[j][1].x, af[j][1].y);
          cv[3] = cvt_pk_bf16(af[j][1].z, af[j][1].w);
          *(u32x4*)&As[(p ^ 1) * ABUF + (w * MF + j) * 512 + l * 8] = cv;
        }
      }
    }
    __syncthreads();
  }

  if constexpr (MODE == 0) {
    int sec = (n0 >= 1536) ? 2 : (n0 >= 768 ? 1 : 0);
    int ncol0 = n0 - sec * 768;
    if (sec < 2) {
#pragma unroll
      for (int nf = 0; nf < 4; ++nf) {
        int nn = wn + nf * 16 + lr;
        float bv = bias[n0 + nn];
        int c = ncol0 + nn;
        int hh = c >> 6, d = c & 63;
#pragma unroll
        for (int mf = 0; mf < MF; ++mf)
#pragma unroll
          for (int rr = 0; rr < 4; ++rr) {
            int m = m0 + wm + mf * 16 + 4 * lg + rr;
            int bb = m >> 11, tt = m & 2047;
            int bh = bb * 12 + hh;
            float v = acc[mf][nf][rr] + bv;
            if (sec == 0) qb[((size_t)bh * T_ + tt) * 64 + d] = f2bf(v * QK_SCALE);
            else          kb[((size_t)bh * T_ + tt) * 64 + d] = f2bf(v);
          }
      }
    } else {
      // V^T: transpose in LDS (p5 key-permutation folded into column), coalesced rows out.
#pragma unroll
      for (int nf = 0; nf < 4; ++nf) {
        int row = wn + nf * 16 + lr;
        float bv = bias[n0 + row];
        int swz = (row & 7) << 3;
#pragma unroll
        for (int mf = 0; mf < MF; ++mf) {
          int pcol0 = wm + (mf >> 1) * 32 + 8 * lg + 4 * (mf & 1);
          u32x2 pk;
          pk[0] = cvt_pk_bf16(acc[mf][nf][0] + bv, acc[mf][nf][1] + bv);
          pk[1] = cvt_pk_bf16(acc[mf][nf][2] + bv, acc[mf][nf][3] + bv);
          *(u32x2*)&S[row * MTILE + (pcol0 ^ swz)] = pk;
        }
      }
      __syncthreads();
      constexpr int CPT = MTILE / 2;
      int rowo = tid >> 1, half = tid & 1;
      int c = ncol0 + rowo;
      int d = c & 63, hh = c >> 6;
      int bh = (m0 >> 11) * 12 + hh;
      u16* dst = vpb + ((size_t)bh * 64 + d) * T_ + (m0 & 2047) + half * CPT;
      int swzo = (rowo & 7) << 3;
#pragma unroll
      for (int i = 0; i < CPT / 8; ++i) {
        int col = half * CPT + i * 8;
        uint4 v = *(const uint4*)&S[rowo * MTILE + (col ^ swzo)];
        *(uint4*)&dst[i * 8] = v;
      }
    }
  } else {
#pragma unroll
    for (int nf = 0; nf < 4; ++nf) {
      int n = n0 + wn + nf * 16 + lr;
      float bv = bias[n];
#pragma unroll
      for (int mf = 0; mf < MF; ++mf)
#pragma unroll
        for (int rr = 0; rr < 4; ++rr) {
          int m = m0 + wm + mf * 16 + 4 * lg + rr;
          out[(size_t)m * 768 + n] = acc[mf][nf][rr] + bv;
        }
    }
  }
}

// ---------------- flash attention (8 waves key-split, 2 tiles per barrier) ----------------
// Identical to R15/R16 (verified).

__global__ __launch_bounds__(512) void attn_kernel(const u16* __restrict__ Q,
                                                   const u16* __restrict__ K,
                                                   const u16* __restrict__ Vp,
                                                   u16* __restrict__ O) {
  __shared__ u16 sh[32768];  // K bufs 4x4096 [0..16384), V bufs 4x4096 [16384..32768)
  int tid = threadIdx.x;
  int w = tid >> 6, l = tid & 63, lg = l >> 4, lr = l & 15;
  int i = w >> 1, j = w & 1;
  int idx = blockIdx.x;
  int head = idx % 24;                 // 24 % 8 == 0: same head -> same XCD (L2 reuse)
  int qblk = 31 - idx / 24;            // big-work blocks dispatch first
  int b = head / 12, h = head % 12;
  int q0 = qblk * 64;
  int q0w = q0 + i * 16;               // this wave's 16 q-rows
  const u16* Qb = Q + (size_t)head * T_ * 64;
  const u16* Kb = K + (size_t)head * T_ * 64;
  const u16* Vb = Vp + (size_t)head * 64 * T_;

  short8 qf0 = *(const short8*)&Qb[(size_t)(q0w + lr) * 64 + 8 * lg];
  short8 qf1 = *(const short8*)&Qb[(size_t)(q0w + lr) * 64 + 32 + 8 * lg];

  f32x4 ao[4] = {};
  float lrow = 0.f;                    // per-lane partial (this wave's key half)
  int rsub = l >> 3;
  int scs = ((l & 7) ^ rsub) * 8;
  int row = w * 8 + rsub;              // staging row
  const int nt = qblk + 1;

  // prologue: stage tiles 0 and 1 into bufs 0,1
  gload16(&Kb[(size_t)row * 64 + scs], &sh[w * 512]);
  gload16(&Vb[(size_t)row * T_ + scs], &sh[16384 + w * 512]);
  if (nt > 1) {
    gload16(&Kb[(size_t)(64 + row) * 64 + scs], &sh[4096 + w * 512]);
    gload16(&Vb[(size_t)row * T_ + 64 + scs], &sh[16384 + 4096 + w * 512]);
  }
  __syncthreads();

  for (int tp = 0; tp < nt; tp += 2) {
    int p = (tp >> 1) & 1;
    if (tp + 2 < nt) {
      int base = ((p ^ 1) * 2) * 4096;
      gload16(&Kb[(size_t)((tp + 2) * 64 + row) * 64 + scs], &sh[base + w * 512]);
      gload16(&Vb[(size_t)row * T_ + (tp + 2) * 64 + scs], &sh[16384 + base + w * 512]);
    }
    if (tp + 3 < nt) {
      int base = ((p ^ 1) * 2 + 1) * 4096;
      gload16(&Kb[(size_t)((tp + 3) * 64 + row) * 64 + scs], &sh[base + w * 512]);
      gload16(&Vb[(size_t)row * T_ + (tp + 3) * 64 + scs], &sh[16384 + base + w * 512]);
    }
#pragma unroll
    for (int sub = 0; sub < 2; ++sub) {
      int t = tp + sub;
      if (t < nt) {
        int k0 = t * 64;
        if (k0 + 32 * j <= q0w + 15) {   // wave-uniform: skip all-masked key-half
          const u16* ks = sh + (p * 2 + sub) * 4096;
          const u16* vs = sh + 16384 + (p * 2 + sub) * 4096;
          short8 ka0[2], ka1[2], va[4];
#pragma unroll
          for (int g = 0; g < 2; ++g) {
            int kg = 2 * j + g;
            ka0[g] = *(const short8*)&ks[(kg * 16 + lr) * 64 + ((lg ^ (lr & 7)) * 8)];
            ka1[g] = *(const short8*)&ks[(kg * 16 + lr) * 64 + (((4 + lg) ^ (lr & 7)) * 8)];
          }
#pragma unroll
          for (int dt = 0; dt < 4; ++dt)
            va[dt] = *(const short8*)&vs[(dt * 16 + lr) * 64 + (((4 * j + lg) ^ (lr & 7)) * 8)];
          f32x4 sm[2];
          __builtin_amdgcn_s_setprio(1);
#pragma unroll
          for (int g = 0; g < 2; ++g) {
            f32x4 z = {};
            z = mfma_bf16(ka0[g], qf0, z);
            z = mfma_bf16(ka1[g], qf1, z);
            sm[g] = z;
          }
          __builtin_amdgcn_s_setprio(0);
          float sv[8];
          float ps = 0.f;
          bool needmask = (t == nt - 1) && (32 * j + 31 > 16 * i);
          if (needmask) {
            int qa = q0w + lr;
#pragma unroll
            for (int g = 0; g < 2; ++g)
#pragma unroll
              for (int rr = 0; rr < 4; ++rr) {
                int key = k0 + (2 * j + g) * 16 + 4 * lg + rr;
                float x = (key <= qa) ? sm[g][rr] : -1e30f;
                float pv = __builtin_amdgcn_exp2f(x);   // exp2(-1e30) = 0
                sv[g * 4 + rr] = pv;
                ps += pv;
              }
          } else {
#pragma unroll
            for (int g = 0; g < 2; ++g)
#pragma unroll
              for (int rr = 0; rr < 4; ++rr) {
                float pv = __builtin_amdgcn_exp2f(sm[g][rr]);
                sv[g * 4 + rr] = pv;
                ps += pv;
              }
          }
          lrow += ps;
          u32x4 uu;
          uu[0] = cvt_pk_bf16(sv[0], sv[1]);
          uu[1] = cvt_pk_bf16(sv[2], sv[3]);
          uu[2] = cvt_pk_bf16(sv[4], sv[5]);
          uu[3] = cvt_pk_bf16(sv[6], sv[7]);
          short8 pb = __builtin_bit_cast(short8, uu);
          __builtin_amdgcn_s_setprio(1);
#pragma unroll
          for (int dt = 0; dt < 4; ++dt)
            ao[dt] = mfma_bf16(va[dt], pb, ao[dt]);
          __builtin_amdgcn_s_setprio(0);
        }
      }
    }
    __syncthreads();
  }

  // reduce partial row-sums within wave (lanes {l, l^16, l^32, l^48} share q = lr)
  lrow += __shfl_xor(lrow, 16);
  lrow += __shfl_xor(lrow, 32);

  // merge key-half partials: j=1 writes (ao, lrow) to LDS; j=0 adds.
  float* aoL = (float*)sh;                    // [4][64][16] f32 = 16 KB
  float* lrL = (float*)(sh + 8192);           // [4][64] f32 = 1 KB
  if (j == 1) {
#pragma unroll
    for (int dt = 0; dt < 4; ++dt)
      *(f32x4*)&aoL[(i * 64 + l) * 16 + dt * 4] = ao[dt];
    lrL[i * 64 + l] = lrow;
  }
  __syncthreads();
  if (j == 0) {
#pragma unroll
    for (int dt = 0; dt < 4; ++dt)
      ao[dt] += *(const f32x4*)&aoL[(i * 64 + l) * 16 + dt * 4];
    lrow += lrL[i * 64 + l];
    // epilogue: normalize + transpose O^T(d,q) -> O(q,d) via per-i LDS region
    u16* ow = sh + 9216 + i * 1152;   // [16][72]
    float inv = 1.0f / lrow;
#pragma unroll
    for (int dt = 0; dt < 4; ++dt) {
      u32x2 pk;
      pk[0] = cvt_pk_bf16(ao[dt][0] * inv, ao[dt][1] * inv);
      pk[1] = cvt_pk_bf16(ao[dt][2] * inv, ao[dt][3] * inv);
      *(u32x2*)&ow[lr * 72 + dt * 16 + 4 * lg] = pk;
    }
    asm volatile("s_waitcnt lgkmcnt(0)" ::: "memory");  // wave-local write->read
    int r = l >> 2, hc = l & 3;
    const u16* srow = sh + 9216 + i * 1152 + r * 72 + hc * 16;
    u16* dst = O + ((size_t)(b * T_ + q0w + r)) * 768 + h * 64 + hc * 16;
    *(uint4*)&dst[0] = *(const uint4*)&srow[0];
    *(uint4*)&dst[8] = *(const uint4*)&srow[8];
  }
}

// ---------------- launch ----------------

extern "C" void kernel_launch(void* const* d_in, const int* in_sizes, int n_in,
                              void* d_out, int out_size, void* d_ws, size_t ws_size,
                              hipStream_t stream) {
  const float* x     = (const float*)d_in[0];
  const float* Wqkv  = (const float*)d_in[1];
  const float* bqkv  = (const float*)d_in[2];
  const float* Wproj = (const float*)d_in[3];
  const float* bproj = (const float*)d_in[4];
  float* out = (float*)d_out;
  char* ws = (char*)d_ws;
  u16* wqkvT  = (u16*)(ws + 6291456);      // 2304*768*2      = 3538944
  u16* wprojT = (u16*)(ws + 9830400);      // 768*768*2       = 1179648
  u16* qb     = (u16*)(ws + 11010048);     // 24*2048*64*2    = 6291456
  u16* kb     = (u16*)(ws + 17301504);     // 6291456
  u16* vpb    = (u16*)(ws + 23592960);     // 6291456
  u16* ob     = (u16*)(ws + 29884416);     // 6291456  (total 36175872)

  prep_kernel<<<2304, 256, 0, stream>>>(Wqkv, Wproj, wqkvT, wprojT);
  gemm_kernel<0, 64><<<dim3(18, 64), 256, 0, stream>>>(x, nullptr, wqkvT, bqkv, qb, kb, vpb, nullptr);
  attn_kernel<<<768, 512, 0, stream>>>(qb, kb, vpb, ob);
  gemm_kernel<1, 32><<<dim3(6, 128), 256, 0, stream>>>(nullptr, ob, wprojT, bproj, nullptr, nullptr, nullptr, out);
}

// Round 18
// 72.254 us; speedup vs baseline: 1.0709x; 1.0709x over previous
//
#include <hip/hip_runtime.h>
#include <stdint.h>

typedef short short8 __attribute__((ext_vector_type(8)));
typedef short short4v __attribute__((ext_vector_type(4)));
typedef float f32x4 __attribute__((ext_vector_type(4)));
typedef unsigned int u32x2 __attribute__((ext_vector_type(2)));
typedef unsigned int u32x4 __attribute__((ext_vector_type(4)));
typedef unsigned short u16;
typedef unsigned int u32;

#define T_ 2048
#define QK_SCALE 0.180336878f   // 0.125 * log2(e): softmax in log2 domain

__device__ inline u16 f2bf(float f) {
  unsigned u = __builtin_bit_cast(unsigned, f);
  u += 0x7fffu + ((u >> 16) & 1u);   // RNE; inputs finite
  return (u16)(u >> 16);
}

__device__ inline u32 cvt_pk_bf16(float lo, float hi) {
  u32 r;
  asm("v_cvt_pk_bf16_f32 %0, %1, %2" : "=v"(r) : "v"(lo), "v"(hi));
  return r;
}

__device__ inline f32x4 mfma_bf16(short8 a, short8 b, f32x4 c) {
  return __builtin_amdgcn_mfma_f32_16x16x32_bf16(a, b, c, 0, 0, 0);
}

// async global->LDS, 16B per lane; lds base must be wave-uniform
__device__ inline void gload16(const u16* g, u16* l) {
  __builtin_amdgcn_global_load_lds(
      (const __attribute__((address_space(1))) void*)g,
      (__attribute__((address_space(3))) void*)l, 16, 0, 0);
}

// ---------------- fused prep: convert x + transpose-convert both weights ----------------

__device__ inline void tile_transpose(const float* __restrict__ W, u16* __restrict__ Wt,
                                      int R, int Ccols, int c0, int r0, int t,
                                      float (*tile)[33]) {
  int tr = t >> 3, tc = (t & 7) * 4;
  float4 v = *(const float4*)&W[(size_t)(r0 + tr) * Ccols + c0 + tc];
  tile[tr][tc + 0] = v.x; tile[tr][tc + 1] = v.y;
  tile[tr][tc + 2] = v.z; tile[tr][tc + 3] = v.w;
  __syncthreads();
  short4v o;
#pragma unroll
  for (int i = 0; i < 4; ++i) o[i] = (short)f2bf(tile[tc + i][tr]);
  *(short4v*)&Wt[(size_t)(c0 + tr) * R + r0 + tc] = o;
}

__global__ __launch_bounds__(256) void prep_kernel(const float* __restrict__ x,
                                                   const float* __restrict__ Wqkv,
                                                   const float* __restrict__ Wproj,
                                                   u16* __restrict__ xb,
                                                   u16* __restrict__ wqkvT,
                                                   u16* __restrict__ wprojT) {
  __shared__ float tile[32][33];
  int bid = blockIdx.x, t = threadIdx.x;
  if (bid < 3072) {
    int i = (bid * 256 + t) * 4;
    float4 v = *(const float4*)&x[i];
    short4v o;
    o[0] = (short)f2bf(v.x); o[1] = (short)f2bf(v.y);
    o[2] = (short)f2bf(v.z); o[3] = (short)f2bf(v.w);
    *(short4v*)&xb[i] = o;
  } else if (bid < 3072 + 1728) {
    int t2 = bid - 3072;
    tile_transpose(Wqkv, wqkvT, 768, 2304, (t2 % 72) * 32, (t2 / 72) * 32, t, tile);
  } else {
    int t3 = bid - 4800;
    tile_transpose(Wproj, wprojT, 768, 768, (t3 % 24) * 32, (t3 / 24) * 32, t, tile);
  }
}

// ---------------- MTILE x 128 GEMM, LDS double-buffered, 1 barrier/iter ----------------
// MODE 0 (MTILE=64): qkv epilogue; MODE 1 (MTILE=32): proj epilogue.

template <int MODE, int MTILE>
__global__ __launch_bounds__(256) void gemm_kernel(const u16* __restrict__ A,
                                                   const u16* __restrict__ Bt,
                                                   const float* __restrict__ bias,
                                                   u16* __restrict__ qb,
                                                   u16* __restrict__ kb,
                                                   u16* __restrict__ vpb,
                                                   float* __restrict__ out) {
  constexpr int MF = MTILE / 32;            // m-fragments per wave
  constexpr int ABUF = MTILE * 64;          // per-buffer A size (u16)
  __shared__ u16 S[2 * ABUF + 2 * 8192];    // As dbuf | Bs dbuf
  u16* As = S;
  u16* Bs = S + 2 * ABUF;
  int tid = threadIdx.x, w = tid >> 6, l = tid & 63, lg = l >> 4, lr = l & 15;
  int nwg = gridDim.x * gridDim.y;
  int hw = blockIdx.y * gridDim.x + blockIdx.x;
  int logical = (hw & 7) * (nwg >> 3) + (hw >> 3);
  int n0 = (logical % gridDim.x) * 128, m0 = (logical / gridDim.x) * MTILE;
  int wm = (w >> 1) * (MTILE / 2), wn = (w & 1) * 64;
  f32x4 acc[MF][4] = {};
  int rsub = l >> 3;
  int sc = ((l & 7) ^ rsub) * 8;

  // prologue: stage tile 0 into buf 0
#pragma unroll
  for (int j = 0; j < MF; ++j) {
    int row = w * (MTILE / 4) + j * 8 + rsub;
    gload16(&A[(size_t)(m0 + row) * 768 + sc], &As[(w * MF + j) * 512]);
  }
#pragma unroll
  for (int j = 0; j < 4; ++j) {
    int row = w * 32 + j * 8 + rsub;
    gload16(&Bt[(size_t)(n0 + row) * 768 + sc], &Bs[(w * 4 + j) * 512]);
  }
  __syncthreads();

  for (int kt = 0; kt < 12; ++kt) {
    int p = kt & 1;
    if (kt + 1 < 12) {
      int k1 = (kt + 1) * 64;
#pragma unroll
      for (int j = 0; j < MF; ++j) {
        int row = w * (MTILE / 4) + j * 8 + rsub;
        gload16(&A[(size_t)(m0 + row) * 768 + k1 + sc], &As[(p ^ 1) * ABUF + (w * MF + j) * 512]);
      }
#pragma unroll
      for (int j = 0; j < 4; ++j) {
        int row = w * 32 + j * 8 + rsub;
        gload16(&Bt[(size_t)(n0 + row) * 768 + k1 + sc], &Bs[(p ^ 1) * 8192 + (w * 4 + j) * 512]);
      }
    }
    const u16* Ap = As + p * ABUF;
    const u16* Bp = Bs + p * 8192;
    short8 a[MF][2], b[4][2];
#pragma unroll
    for (int h = 0; h < 2; ++h) {
#pragma unroll
      for (int mf = 0; mf < MF; ++mf) {
        int cw = ((h * 4 + lg) ^ (lr & 7)) * 8;
        a[mf][h] = *(const short8*)&Ap[(wm + mf * 16 + lr) * 64 + cw];
      }
#pragma unroll
      for (int nf = 0; nf < 4; ++nf) {
        int cw = ((h * 4 + lg) ^ (lr & 7)) * 8;
        b[nf][h] = *(const short8*)&Bp[(wn + nf * 16 + lr) * 64 + cw];
      }
    }
#pragma unroll
    for (int h = 0; h < 2; ++h)
#pragma unroll
      for (int mf = 0; mf < MF; ++mf)
#pragma unroll
        for (int nf = 0; nf < 4; ++nf)
          acc[mf][nf] = mfma_bf16(a[mf][h], b[nf][h], acc[mf][nf]);
    __syncthreads();
  }

  if constexpr (MODE == 0) {
    int sec = (n0 >= 1536) ? 2 : (n0 >= 768 ? 1 : 0);
    int ncol0 = n0 - sec * 768;
    if (sec < 2) {
#pragma unroll
      for (int nf = 0; nf < 4; ++nf) {
        int nn = wn + nf * 16 + lr;
        float bv = bias[n0 + nn];
        int c = ncol0 + nn;
        int hh = c >> 6, d = c & 63;
#pragma unroll
        for (int mf = 0; mf < MF; ++mf)
#pragma unroll
          for (int rr = 0; rr < 4; ++rr) {
            int m = m0 + wm + mf * 16 + 4 * lg + rr;
            int bb = m >> 11, tt = m & 2047;
            int bh = bb * 12 + hh;
            float v = acc[mf][nf][rr] + bv;
            if (sec == 0) qb[((size_t)bh * T_ + tt) * 64 + d] = f2bf(v * QK_SCALE);
            else          kb[((size_t)bh * T_ + tt) * 64 + d] = f2bf(v);
          }
      }
    } else {
      // V^T: transpose in LDS (p5 key-permutation folded into column), coalesced rows out.
      // (reuses S[0..8192): barrier-protected, loop is done with LDS)
#pragma unroll
      for (int nf = 0; nf < 4; ++nf) {
        int row = wn + nf * 16 + lr;
        float bv = bias[n0 + row];
        int swz = (row & 7) << 3;
#pragma unroll
        for (int mf = 0; mf < MF; ++mf) {
          int pcol0 = wm + (mf >> 1) * 32 + 8 * lg + 4 * (mf & 1);
          u32x2 pk;
          pk[0] = cvt_pk_bf16(acc[mf][nf][0] + bv, acc[mf][nf][1] + bv);
          pk[1] = cvt_pk_bf16(acc[mf][nf][2] + bv, acc[mf][nf][3] + bv);
          *(u32x2*)&S[row * MTILE + (pcol0 ^ swz)] = pk;
        }
      }
      __syncthreads();
      constexpr int CPT = MTILE / 2;
      int rowo = tid >> 1, half = tid & 1;
      int c = ncol0 + rowo;
      int d = c & 63, hh = c >> 6;
      int bh = (m0 >> 11) * 12 + hh;
      u16* dst = vpb + ((size_t)bh * 64 + d) * T_ + (m0 & 2047) + half * CPT;
      int swzo = (rowo & 7) << 3;
#pragma unroll
      for (int i = 0; i < CPT / 8; ++i) {
        int col = half * CPT + i * 8;
        uint4 v = *(const uint4*)&S[rowo * MTILE + (col ^ swzo)];
        *(uint4*)&dst[i * 8] = v;
      }
    }
  } else {
#pragma unroll
    for (int nf = 0; nf < 4; ++nf) {
      int n = n0 + wn + nf * 16 + lr;
      float bv = bias[n];
#pragma unroll
      for (int mf = 0; mf < MF; ++mf)
#pragma unroll
        for (int rr = 0; rr < 4; ++rr) {
          int m = m0 + wm + mf * 16 + 4 * lg + rr;
          out[(size_t)m * 768 + n] = acc[mf][nf][rr] + bv;
        }
    }
  }
}

// ---------------- flash attention (8 waves key-split, 2 tiles per barrier) ----------------
// Identical to R15/R16 (verified).

__global__ __launch_bounds__(512) void attn_kernel(const u16* __restrict__ Q,
                                                   const u16* __restrict__ K,
                                                   const u16* __restrict__ Vp,
                                                   u16* __restrict__ O) {
  __shared__ u16 sh[32768];  // K bufs 4x4096 [0..16384), V bufs 4x4096 [16384..32768)
  int tid = threadIdx.x;
  int w = tid >> 6, l = tid & 63, lg = l >> 4, lr = l & 15;
  int i = w >> 1, j = w & 1;
  int idx = blockIdx.x;
  int head = idx % 24;                 // 24 % 8 == 0: same head -> same XCD (L2 reuse)
  int qblk = 31 - idx / 24;            // big-work blocks dispatch first
  int b = head / 12, h = head % 12;
  int q0 = qblk * 64;
  int q0w = q0 + i * 16;               // this wave's 16 q-rows
  const u16* Qb = Q + (size_t)head * T_ * 64;
  const u16* Kb = K + (size_t)head * T_ * 64;
  const u16* Vb = Vp + (size_t)head * 64 * T_;

  short8 qf0 = *(const short8*)&Qb[(size_t)(q0w + lr) * 64 + 8 * lg];
  short8 qf1 = *(const short8*)&Qb[(size_t)(q0w + lr) * 64 + 32 + 8 * lg];

  f32x4 ao[4] = {};
  float lrow = 0.f;                    // per-lane partial (this wave's key half)
  int rsub = l >> 3;
  int scs = ((l & 7) ^ rsub) * 8;
  int row = w * 8 + rsub;              // staging row
  const int nt = qblk + 1;

  // prologue: stage tiles 0 and 1 into bufs 0,1
  gload16(&Kb[(size_t)row * 64 + scs], &sh[w * 512]);
  gload16(&Vb[(size_t)row * T_ + scs], &sh[16384 + w * 512]);
  if (nt > 1) {
    gload16(&Kb[(size_t)(64 + row) * 64 + scs], &sh[4096 + w * 512]);
    gload16(&Vb[(size_t)row * T_ + 64 + scs], &sh[16384 + 4096 + w * 512]);
  }
  __syncthreads();

  for (int tp = 0; tp < nt; tp += 2) {
    int p = (tp >> 1) & 1;
    if (tp + 2 < nt) {
      int base = ((p ^ 1) * 2) * 4096;
      gload16(&Kb[(size_t)((tp + 2) * 64 + row) * 64 + scs], &sh[base + w * 512]);
      gload16(&Vb[(size_t)row * T_ + (tp + 2) * 64 + scs], &sh[16384 + base + w * 512]);
    }
    if (tp + 3 < nt) {
      int base = ((p ^ 1) * 2 + 1) * 4096;
      gload16(&Kb[(size_t)((tp + 3) * 64 + row) * 64 + scs], &sh[base + w * 512]);
      gload16(&Vb[(size_t)row * T_ + (tp + 3) * 64 + scs], &sh[16384 + base + w * 512]);
    }
#pragma unroll
    for (int sub = 0; sub < 2; ++sub) {
      int t = tp + sub;
      if (t < nt) {
        int k0 = t * 64;
        if (k0 + 32 * j <= q0w + 15) {   // wave-uniform: skip all-masked key-half
          const u16* ks = sh + (p * 2 + sub) * 4096;
          const u16* vs = sh + 16384 + (p * 2 + sub) * 4096;
          short8 ka0[2], ka1[2], va[4];
#pragma unroll
          for (int g = 0; g < 2; ++g) {
            int kg = 2 * j + g;
            ka0[g] = *(const short8*)&ks[(kg * 16 + lr) * 64 + ((lg ^ (lr & 7)) * 8)];
            ka1[g] = *(const short8*)&ks[(kg * 16 + lr) * 64 + (((4 + lg) ^ (lr & 7)) * 8)];
          }
#pragma unroll
          for (int dt = 0; dt < 4; ++dt)
            va[dt] = *(const short8*)&vs[(dt * 16 + lr) * 64 + (((4 * j + lg) ^ (lr & 7)) * 8)];
          f32x4 sm[2];
          __builtin_amdgcn_s_setprio(1);
#pragma unroll
          for (int g = 0; g < 2; ++g) {
            f32x4 z = {};
            z = mfma_bf16(ka0[g], qf0, z);
            z = mfma_bf16(ka1[g], qf1, z);
            sm[g] = z;
          }
          __builtin_amdgcn_s_setprio(0);
          float sv[8];
          float ps = 0.f;
          bool needmask = (t == nt - 1) && (32 * j + 31 > 16 * i);
          if (needmask) {
            int qa = q0w + lr;
#pragma unroll
            for (int g = 0; g < 2; ++g)
#pragma unroll
              for (int rr = 0; rr < 4; ++rr) {
                int key = k0 + (2 * j + g) * 16 + 4 * lg + rr;
                float x = (key <= qa) ? sm[g][rr] : -1e30f;
                float pv = __builtin_amdgcn_exp2f(x);   // exp2(-1e30) = 0
                sv[g * 4 + rr] = pv;
                ps += pv;
              }
          } else {
#pragma unroll
            for (int g = 0; g < 2; ++g)
#pragma unroll
              for (int rr = 0; rr < 4; ++rr) {
                float pv = __builtin_amdgcn_exp2f(sm[g][rr]);
                sv[g * 4 + rr] = pv;
                ps += pv;
              }
          }
          lrow += ps;
          u32x4 uu;
          uu[0] = cvt_pk_bf16(sv[0], sv[1]);
          uu[1] = cvt_pk_bf16(sv[2], sv[3]);
          uu[2] = cvt_pk_bf16(sv[4], sv[5]);
          uu[3] = cvt_pk_bf16(sv[6], sv[7]);
          short8 pb = __builtin_bit_cast(short8, uu);
          __builtin_amdgcn_s_setprio(1);
#pragma unroll
          for (int dt = 0; dt < 4; ++dt)
            ao[dt] = mfma_bf16(va[dt], pb, ao[dt]);
          __builtin_amdgcn_s_setprio(0);
        }
      }
    }
    __syncthreads();
  }

  // reduce partial row-sums within wave (lanes {l, l^16, l^32, l^48} share q = lr)
  lrow += __shfl_xor(lrow, 16);
  lrow += __shfl_xor(lrow, 32);

  // merge key-half partials: j=1 writes (ao, lrow) to LDS; j=0 adds.
  float* aoL = (float*)sh;                    // [4][64][16] f32 = 16 KB
  float* lrL = (float*)(sh + 8192);           // [4][64] f32 = 1 KB
  if (j == 1) {
#pragma unroll
    for (int dt = 0; dt < 4; ++dt)
      *(f32x4*)&aoL[(i * 64 + l) * 16 + dt * 4] = ao[dt];
    lrL[i * 64 + l] = lrow;
  }
  __syncthreads();
  if (j == 0) {
#pragma unroll
    for (int dt = 0; dt < 4; ++dt)
      ao[dt] += *(const f32x4*)&aoL[(i * 64 + l) * 16 + dt * 4];
    lrow += lrL[i * 64 + l];
    // epilogue: normalize + transpose O^T(d,q) -> O(q,d) via per-i LDS region
    u16* ow = sh + 9216 + i * 1152;   // [16][72]
    float inv = 1.0f / lrow;
#pragma unroll
    for (int dt = 0; dt < 4; ++dt) {
      u32x2 pk;
      pk[0] = cvt_pk_bf16(ao[dt][0] * inv, ao[dt][1] * inv);
      pk[1] = cvt_pk_bf16(ao[dt][2] * inv, ao[dt][3] * inv);
      *(u32x2*)&ow[lr * 72 + dt * 16 + 4 * lg] = pk;
    }
    asm volatile("s_waitcnt lgkmcnt(0)" ::: "memory");  // wave-local write->read
    int r = l >> 2, hc = l & 3;
    const u16* srow = sh + 9216 + i * 1152 + r * 72 + hc * 16;
    u16* dst = O + ((size_t)(b * T_ + q0w + r)) * 768 + h * 64 + hc * 16;
    *(uint4*)&dst[0] = *(const uint4*)&srow[0];
    *(uint4*)&dst[8] = *(const uint4*)&srow[8];
  }
}

// ---------------- launch ----------------

extern "C" void kernel_launch(void* const* d_in, const int* in_sizes, int n_in,
                              void* d_out, int out_size, void* d_ws, size_t ws_size,
                              hipStream_t stream) {
  const float* x     = (const float*)d_in[0];
  const float* Wqkv  = (const float*)d_in[1];
  const float* bqkv  = (const float*)d_in[2];
  const float* Wproj = (const float*)d_in[3];
  const float* bproj = (const float*)d_in[4];
  float* out = (float*)d_out;
  char* ws = (char*)d_ws;
  u16* xb     = (u16*)(ws);                // 4096*768*2      = 6291456
  u16* wqkvT  = (u16*)(ws + 6291456);      // 2304*768*2      = 3538944
  u16* wprojT = (u16*)(ws + 9830400);      // 768*768*2       = 1179648
  u16* qb     = (u16*)(ws + 11010048);     // 24*2048*64*2    = 6291456
  u16* kb     = (u16*)(ws + 17301504);     // 6291456
  u16* vpb    = (u16*)(ws + 23592960);     // 6291456
  u16* ob     = (u16*)(ws + 29884416);     // 6291456  (total 36175872)

  prep_kernel<<<5376, 256, 0, stream>>>(x, Wqkv, Wproj, xb, wqkvT, wprojT);
  gemm_kernel<0, 64><<<dim3(18, 64), 256, 0, stream>>>(xb, wqkvT, bqkv, qb, kb, vpb, nullptr);
  attn_kernel<<<768, 512, 0, stream>>>(qb, kb, vpb, ob);
  gemm_kernel<1, 32><<<dim3(6, 128), 256, 0, stream>>>(ob, wprojT, bproj, nullptr, nullptr, nullptr, out);
}